// Round 11
// baseline (964.256 us; speedup 1.0000x reference)
//
#include <hip/hip_runtime.h>
#include <cmath>

#define DMODEL  1024
#define DINNER  2048
#define NHEADS  32
#define CONVDIM 2176
#define DPROJ   4256
#define VOCAB   50257
#define NBLK_V  400            // LM-head n-blocks (400*128 = 51200 >= VOCAB)
#define VOCABP  (NBLK_V * 128)
#define CLEN    32
#define NCHUNK  32

typedef float f32x4 __attribute__((ext_vector_type(4)));
typedef float f32x2 __attribute__((ext_vector_type(2)));
typedef unsigned short u16;
typedef u16 u16x4 __attribute__((ext_vector_type(4)));
typedef u16 u16x8 __attribute__((ext_vector_type(8)));
typedef __bf16 bf16x8 __attribute__((ext_vector_type(8)));

__device__ __forceinline__ u16 f2bf(float f) {
  unsigned u = __builtin_bit_cast(unsigned, f);
  u += 0x7FFFu + ((u >> 16) & 1u);
  return (u16)(u >> 16);
}
__device__ __forceinline__ float silu_f(float x) { return x / (1.f + expf(-x)); }

__device__ __forceinline__ void gload16(const u16* g, u16* l) {
  __builtin_amdgcn_global_load_lds(
      (const __attribute__((address_space(1))) void*)g,
      (__attribute__((address_space(3))) void*)l,
      16, 0, 0);
}
__device__ __forceinline__ void vm_wait0() { asm volatile("s_waitcnt vmcnt(0)" ::: "memory"); }
__device__ __forceinline__ void barrier_() {
  __builtin_amdgcn_s_barrier();
  __builtin_amdgcn_sched_barrier(0);
}

// ---------------------------------------------------------------- 128x128 GEMM
// R7-proven: 4 waves, BK=32, 3-deep LDS, counted vmcnt(4); bf16 A and B.
// Swizzle: 64B rows, phys chunk = data ^ ((row>>1)&3); conflict-free.
__global__ __launch_bounds__(256) void gemm_bf16(
    const u16* __restrict__ A, const u16* __restrict__ B,
    float* __restrict__ C, int N, int K, int kslice)
{
  __shared__ alignas(128) u16 As[3 * 4096];
  __shared__ alignas(128) u16 Bs[3 * 4096];
  const int tid = threadIdx.x;
  const int m0 = blockIdx.x << 7;
  const int n0 = blockIdx.y << 7;
  const int lane = tid & 63, wid = tid >> 6;
  const int wm = (wid >> 1) << 6, wn = (wid & 1) << 6;
  const int lr = lane & 15, kg = lane >> 4;

  const int srow = wid * 16 + (lane >> 2);
  const int scol = ((lane & 3) ^ ((lane >> 3) & 3)) << 3;
  const u16* gA = A + (size_t)(m0 + srow) * K + scol;
  const u16* gB = B + (size_t)(n0 + srow) * K + scol;

  f32x4 acc[4][4];
#pragma unroll
  for (int i = 0; i < 4; ++i)
#pragma unroll
    for (int j = 0; j < 4; ++j) acc[i][j] = (f32x4){0.f, 0.f, 0.f, 0.f};

  const int kb = blockIdx.z * kslice;
  const int nt = kslice >> 5;

  auto stage = [&](int buf, int t) {
    const int ko = kb + (t << 5);
#pragma unroll
    for (int i = 0; i < 2; ++i) {
      gload16(gA + ko + (size_t)i * 64 * K, &As[buf * 4096 + i * 2048 + wid * 512]);
      gload16(gB + ko + (size_t)i * 64 * K, &Bs[buf * 4096 + i * 2048 + wid * 512]);
    }
  };

  stage(0, 0);
  stage(1, 1);
  int b0 = 0, b1 = 1, b2 = 2;
  const int cxr = (lr >> 1) & 3;
  for (int t = 0; t < nt; ++t) {
    if (t == nt - 1) vm_wait0();
    else             asm volatile("s_waitcnt vmcnt(4)" ::: "memory");
    __builtin_amdgcn_s_barrier();
    if (t + 2 < nt) stage(b2, t + 2);
    bf16x8 af[4], bfr[4];
    const int po = (kg ^ cxr) << 3;
#pragma unroll
    for (int f = 0; f < 4; ++f) {
      af[f]  = *(const bf16x8*)&As[b0 * 4096 + (wm + f * 16 + lr) * 32 + po];
      bfr[f] = *(const bf16x8*)&Bs[b0 * 4096 + (wn + f * 16 + lr) * 32 + po];
    }
#pragma unroll
    for (int i = 0; i < 4; ++i)
#pragma unroll
      for (int j = 0; j < 4; ++j)
        acc[i][j] = __builtin_amdgcn_mfma_f32_16x16x32_bf16(af[i], bfr[j], acc[i][j], 0, 0, 0);
    int tmp = b0; b0 = b1; b1 = b2; b2 = tmp;
  }

  const int mr = (lane >> 4) << 2;
  const int nc = lane & 15;
  float* Cw = C + (gridDim.z > 1 ? (size_t)blockIdx.z * 1024 * N : 0);
#pragma unroll
  for (int i = 0; i < 4; ++i)
#pragma unroll
    for (int j = 0; j < 4; ++j) {
      int n = n0 + wn + j * 16 + nc;
      if (n < N) {
#pragma unroll
        for (int e = 0; e < 4; ++e)
          Cw[(size_t)(m0 + wm + i * 16 + mr + e) * N + n] = acc[i][j][e];
      }
    }
}

// ---------------------------------------------------------------- 256x128 GEMM
// R7-proven: 8 waves, BK=32, 3-deep, counted vmcnt(3). Used for fc1 (GLU fused,
// B rows interleaved y0,g0,y1,...; epilogue emits bf16 y*silu(g)).
__global__ __launch_bounds__(512) void gemm256(
    const u16* __restrict__ A, const u16* __restrict__ B,
    u16* __restrict__ glu_out, int N, int K)
{
  __shared__ alignas(128) u16 As[3 * 8192];
  __shared__ alignas(128) u16 Bs[3 * 4096];
  const int tid = threadIdx.x;
  const int m0 = blockIdx.x << 8;
  const int n0 = blockIdx.y << 7;
  const int lane = tid & 63, wid = tid >> 6;
  const int wm = (wid >> 1) << 6, wn = (wid & 1) << 6;
  const int lr = lane & 15, kg = lane >> 4;

  const int srow = wid * 16 + (lane >> 2);
  const int scol = ((lane & 3) ^ ((lane >> 3) & 3)) << 3;
  const u16* gA = A + (size_t)(m0 + srow) * K + scol;
  const u16* gB = B + (size_t)(n0 + srow) * K + scol;

  f32x4 acc[4][4];
#pragma unroll
  for (int i = 0; i < 4; ++i)
#pragma unroll
    for (int j = 0; j < 4; ++j) acc[i][j] = (f32x4){0.f, 0.f, 0.f, 0.f};

  const int nt = K >> 5;

  auto stage = [&](int buf, int t) {
    const int ko = t << 5;
    gload16(gA + ko,                    &As[buf * 8192 + wid * 512]);
    gload16(gA + ko + (size_t)128 * K,  &As[buf * 8192 + 4096 + wid * 512]);
    gload16(gB + ko,                    &Bs[buf * 4096 + wid * 512]);
  };

  stage(0, 0);
  stage(1, 1);
  int b0 = 0, b1 = 1, b2 = 2;
  const int cxr = (lr >> 1) & 3;
  for (int t = 0; t < nt; ++t) {
    if (t == nt - 1) vm_wait0();
    else             asm volatile("s_waitcnt vmcnt(3)" ::: "memory");
    __builtin_amdgcn_s_barrier();
    if (t + 2 < nt) stage(b2, t + 2);
    bf16x8 af[4], bfr[4];
    const int po = (kg ^ cxr) << 3;
#pragma unroll
    for (int f = 0; f < 4; ++f) {
      af[f]  = *(const bf16x8*)&As[b0 * 8192 + (wm + f * 16 + lr) * 32 + po];
      bfr[f] = *(const bf16x8*)&Bs[b0 * 4096 + (wn + f * 16 + lr) * 32 + po];
    }
#pragma unroll
    for (int i = 0; i < 4; ++i)
#pragma unroll
      for (int j = 0; j < 4; ++j)
        acc[i][j] = __builtin_amdgcn_mfma_f32_16x16x32_bf16(af[i], bfr[j], acc[i][j], 0, 0, 0);
    int tmp = b0; b0 = b1; b1 = b2; b2 = tmp;
  }

  const int mr = (lane >> 4) << 2;
  const int nc = lane & 15;
  // interleaved cols: even n -> y[n/2], odd n -> g[n/2]
#pragma unroll
  for (int i = 0; i < 4; ++i)
#pragma unroll
    for (int j = 0; j < 4; ++j)
#pragma unroll
      for (int e = 0; e < 4; ++e) {
        float v = acc[i][j][e];
        float p = __shfl_xor(v, 1);
        if (!(nc & 1)) {
          int q = (n0 + wn + j * 16 + nc) >> 1;
          int row = m0 + wm + i * 16 + mr + e;
          glu_out[(size_t)row * 4096 + q] = f2bf(v * silu_f(p));
        }
      }
}

// ---------------------------------------------------------------- LM-head GEMM
// R7 gemm256 skeleton (8 waves, BM=256, BN=128, BK=32), but B (padded bf16 E)
// is loaded DIRECTLY global/L2 -> registers: no B LDS staging, no B ds_reads.
// LDS-port model: R7 was 16w x 8 reads x 12cyc = 1536cyc vs 320cyc MFMA
// (21% ceiling, matches 23% measured); halving reads -> ~42% ceiling.
// Fixes for R10's failure: 2-iteration B lookahead (two named reg sets,
// pair-unrolled), ONE wait+barrier per K-step, counted vmcnt (6 steady /
// 4 at tail = exact newer-ops-in-flight); B-reg completion left to the
// compiler's automatic waits. A: proven 3-deep global_load_lds (48KB LDS).
// XCD-bijective 1-D grid: 4 m-blocks x 400 n-blocks; each n-tile owned by
// one XCD's L2 (R4-proven). Emits LSE partials (max-then-sum).
__global__ __launch_bounds__(512) void gemm_lm(
    const u16* __restrict__ A, const u16* __restrict__ B,
    float* __restrict__ C, int N, int K, float* __restrict__ lsepart)
{
  __shared__ alignas(128) u16 As[3 * 8192];   // 3 x 256x32
  const int tid = threadIdx.x;
  const int bid = blockIdx.x;
  const int m0 = ((bid >> 3) & 3) << 8;
  const int n0 = ((bid & 7) + ((bid >> 5) << 3)) << 7;
  const int lane = tid & 63, wid = tid >> 6;
  const int wm = (wid >> 1) << 6, wn = (wid & 1) << 6;
  const int lr = lane & 15, kg = lane >> 4;

  const int srow = wid * 16 + (lane >> 2);
  const int scol = ((lane & 3) ^ ((lane >> 3) & 3)) << 3;
  const u16* gA = A + (size_t)(m0 + srow) * K + scol;
  // B fragment source: row n0+wn+f*16+lr, 16B at col kg*8 within k-slice
  const u16* gB = B + (size_t)(n0 + wn + lr) * K + kg * 8;

  f32x4 acc[4][4];
#pragma unroll
  for (int i = 0; i < 4; ++i)
#pragma unroll
    for (int j = 0; j < 4; ++j) acc[i][j] = (f32x4){0.f, 0.f, 0.f, 0.f};

  const int nt = K >> 5;   // 32 for K=1024
  auto stageA = [&](int buf, int t) {
    const int ko = t << 5;
    gload16(gA + ko,                    &As[buf * 8192 + wid * 512]);
    gload16(gA + ko + (size_t)128 * K,  &As[buf * 8192 + 4096 + wid * 512]);
  };

  bf16x8 bE[4], bO[4];   // B reg sets: even tiles / odd tiles
#pragma unroll
  for (int f = 0; f < 4; ++f) bE[f] = *(const bf16x8*)(gB + (size_t)f * 16 * K);
#pragma unroll
  for (int f = 0; f < 4; ++f) bO[f] = *(const bf16x8*)(gB + (size_t)f * 16 * K + 32);
  stageA(0, 0); stageA(1, 1);
  asm volatile("s_waitcnt vmcnt(2)" ::: "memory");   // A(0) done (A(1) in flight)
  barrier_();

  const int po = (kg ^ ((lr >> 1) & 3)) << 3;
  for (int t = 0; t < nt; t += 2) {
    { // even tile t: As[t%3] ready, bE holds B(t)
      bf16x8 af[4];
      const int ab = (t % 3) * 8192;
#pragma unroll
      for (int f = 0; f < 4; ++f)
        af[f] = *(const bf16x8*)&As[ab + (wm + f * 16 + lr) * 32 + po];
      if (t + 2 < nt) stageA((t + 2) % 3, t + 2);
#pragma unroll
      for (int i = 0; i < 4; ++i)
#pragma unroll
        for (int j = 0; j < 4; ++j)
          acc[i][j] = __builtin_amdgcn_mfma_f32_16x16x32_bf16(af[i], bE[j], acc[i][j], 0, 0, 0);
      if (t + 2 < nt) {
#pragma unroll
        for (int f = 0; f < 4; ++f)
          bE[f] = *(const bf16x8*)(gB + (size_t)f * 16 * K + ((t + 2) << 5));
      }
    }
    // wait for A(t+1); newer in flight: stageA(t+2)[2] + loadB(t+2)[4] = 6
    if (t + 1 == nt - 1) asm volatile("s_waitcnt vmcnt(4)" ::: "memory");
    else                 asm volatile("s_waitcnt vmcnt(6)" ::: "memory");
    barrier_();
    { // odd tile t+1: bO holds B(t+1)
      bf16x8 af[4];
      const int ab = ((t + 1) % 3) * 8192;
#pragma unroll
      for (int f = 0; f < 4; ++f)
        af[f] = *(const bf16x8*)&As[ab + (wm + f * 16 + lr) * 32 + po];
      if (t + 3 < nt) stageA((t + 3) % 3, t + 3);
#pragma unroll
      for (int i = 0; i < 4; ++i)
#pragma unroll
        for (int j = 0; j < 4; ++j)
          acc[i][j] = __builtin_amdgcn_mfma_f32_16x16x32_bf16(af[i], bO[j], acc[i][j], 0, 0, 0);
      if (t + 3 < nt) {
#pragma unroll
        for (int f = 0; f < 4; ++f)
          bO[f] = *(const bf16x8*)(gB + (size_t)f * 16 * K + ((t + 3) << 5));
      }
    }
    if (t + 2 < nt) {
      // wait for A(t+2); newer: stageA(t+3)[2] + loadB(t+3)[4] = 6
      asm volatile("s_waitcnt vmcnt(6)" ::: "memory");
      barrier_();
    }
  }

  const int mr = (lane >> 4) << 2;
  const int nc = lane & 15;
#pragma unroll
  for (int i = 0; i < 4; ++i)
#pragma unroll
    for (int j = 0; j < 4; ++j) {
      int n = n0 + wn + j * 16 + nc;
      if (n < N) {
#pragma unroll
        for (int e = 0; e < 4; ++e)
          C[(size_t)(m0 + wm + i * 16 + mr + e) * N + n] = acc[i][j][e];
      }
    }

  // LSE partials (max-then-sum; R7-proven 256-row form)
  __syncthreads();
  float* Ls = (float*)As;    // [256 rows][2 halves][2] = 4KB
#pragma unroll
  for (int i = 0; i < 4; ++i)
#pragma unroll
    for (int e = 0; e < 4; ++e) {
      float pm = -1e30f;
#pragma unroll
      for (int j = 0; j < 4; ++j) {
        int n = n0 + wn + j * 16 + nc;
        if (n < N) pm = fmaxf(pm, acc[i][j][e]);
      }
#pragma unroll
      for (int o = 1; o < 16; o <<= 1) pm = fmaxf(pm, __shfl_xor(pm, o));
      float ps = 0.f;
#pragma unroll
      for (int j = 0; j < 4; ++j) {
        int n = n0 + wn + j * 16 + nc;
        if (n < N) ps += expf(acc[i][j][e] - pm);
      }
#pragma unroll
      for (int o = 1; o < 16; o <<= 1) ps += __shfl_xor(ps, o);
      if (nc == 0) {
        int row = wm + i * 16 + mr + e;
        Ls[row * 4 + (wid & 1) * 2] = pm;
        Ls[row * 4 + (wid & 1) * 2 + 1] = ps;
      }
    }
  __syncthreads();
  if (tid < 256) {
    float pa = Ls[tid * 4], sa = Ls[tid * 4 + 1];
    float pb = Ls[tid * 4 + 2], sb = Ls[tid * 4 + 3];
    float M = fmaxf(pa, pb);
    float S = sa * expf(pa - M) + sb * expf(pb - M);
    ((f32x2*)lsepart)[(size_t)(m0 + tid) * NBLK_V + (n0 >> 7)] = (f32x2){M, S};
  }
}

// ---------------------------------------------------------------- conversions
__global__ void k_cvt8(const float* __restrict__ src, u16* __restrict__ dst, int n8) {
  int i = blockIdx.x * 256 + threadIdx.x;
  if (i >= n8) return;
  f32x4 a = ((const f32x4*)src)[i * 2];
  f32x4 b = ((const f32x4*)src)[i * 2 + 1];
  u16x8 o = { f2bf(a[0]), f2bf(a[1]), f2bf(a[2]), f2bf(a[3]),
              f2bf(b[0]), f2bf(b[1]), f2bf(b[2]), f2bf(b[3]) };
  ((u16x8*)dst)[i] = o;
}

__global__ void k_cvt8_pad(const float* __restrict__ src, u16* __restrict__ dst,
                           int n8, int srcN8) {
  int i = blockIdx.x * 256 + threadIdx.x;
  if (i >= n8) return;
  u16x8 o;
  if (i < srcN8) {
    f32x4 a = ((const f32x4*)src)[i * 2];
    f32x4 b = ((const f32x4*)src)[i * 2 + 1];
    o = (u16x8){ f2bf(a[0]), f2bf(a[1]), f2bf(a[2]), f2bf(a[3]),
                 f2bf(b[0]), f2bf(b[1]), f2bf(b[2]), f2bf(b[3]) };
  } else {
    o = (u16x8){0, 0, 0, 0, 0, 0, 0, 0};
  }
  ((u16x8*)dst)[i] = o;
}

// fc1 weights with y/g row interleave
__global__ void k_cvt_fc1(const float* __restrict__ src, u16* __restrict__ dst, int n8) {
  int i = blockIdx.x * 256 + threadIdx.x;
  if (i >= n8) return;  // n8 = 2*8192*128
  f32x4 a = ((const f32x4*)src)[i * 2];
  f32x4 b = ((const f32x4*)src)[i * 2 + 1];
  u16x8 o = { f2bf(a[0]), f2bf(a[1]), f2bf(a[2]), f2bf(a[3]),
              f2bf(b[0]), f2bf(b[1]), f2bf(b[2]), f2bf(b[3]) };
  int R = i >> 7, col8 = i & 127;
  int layer = R >> 13, r = R & 8191;
  int dstr = (r < 4096) ? (r << 1) : (((r - 4096) << 1) | 1);
  ((u16x8*)dst)[((size_t)(layer << 13) + dstr) * 128 + col8] = o;
}

// ---------------------------------------------------------------- fused LN
__device__ __forceinline__ void ln_write(f32x4 v, const float* __restrict__ w,
                                         u16* __restrict__ out, int t, int tid) {
  float s = v[0] + v[1] + v[2] + v[3];
  float sq = v[0]*v[0] + v[1]*v[1] + v[2]*v[2] + v[3]*v[3];
#pragma unroll
  for (int o = 32; o; o >>= 1) { s += __shfl_down(s, o); sq += __shfl_down(sq, o); }
  __shared__ float sb[4], qb[4];
  if ((tid & 63) == 0) { sb[tid >> 6] = s; qb[tid >> 6] = sq; }
  __syncthreads();
  s = sb[0] + sb[1] + sb[2] + sb[3];
  sq = qb[0] + qb[1] + qb[2] + qb[3];
  float mu = s * (1.f / 1024.f);
  float rstd = rsqrtf(sq * (1.f / 1024.f) - mu * mu + 1e-5f);
  u16x4 o;
#pragma unroll
  for (int e = 0; e < 4; ++e) o[e] = f2bf((v[e] - mu) * rstd * w[tid * 4 + e]);
  ((u16x4*)out)[t * 256 + tid] = o;
}

__global__ void k_ln_embed(const int* __restrict__ idx, const float* __restrict__ E,
                           const float* __restrict__ w, float* __restrict__ hbuf,
                           u16* __restrict__ out) {
  int t = blockIdx.x, tid = threadIdx.x;
  f32x4 v = ((const f32x4*)(E + (size_t)idx[t] * DMODEL))[tid];
  ((f32x4*)hbuf)[t * 256 + tid] = v;
  ln_write(v, w, out, t, tid);
}

__global__ void k_red_ln(const float* __restrict__ part, int S,
                         float* __restrict__ hbuf, const float* __restrict__ w,
                         u16* __restrict__ out) {
  int t = blockIdx.x, tid = threadIdx.x;
  f32x4 v = ((const f32x4*)hbuf)[t * 256 + tid];
  for (int k = 0; k < S; ++k)
    v += ((const f32x4*)part)[(size_t)k * 262144 + t * 256 + tid];
  ((f32x4*)hbuf)[t * 256 + tid] = v;
  ln_write(v, w, out, t, tid);
}

// ---------------------------------------------------------------- conv + dt
__global__ void k_convdt(const float* __restrict__ zx, const float* __restrict__ cw,
                         const float* __restrict__ cb, const float* __restrict__ dtb,
                         const float* __restrict__ alog, float* __restrict__ xbc,
                         float* __restrict__ dtsp, float* __restrict__ dag) {
  int t = blockIdx.y, x = blockIdx.x, tid = threadIdx.x;
  if (x < 8 || tid < 128) {
    int c = x * 256 + tid;
    float acc = cb[c];
#pragma unroll
    for (int k = 0; k < 4; ++k) {
      int tt = t + k - 3;
      if (tt >= 0) acc += zx[(size_t)tt * DPROJ + 2048 + c] * cw[c * 4 + k];
    }
    xbc[(size_t)t * CONVDIM + c] = silu_f(acc);
  } else if (tid < 160) {
    int hh = tid - 128;
    float raw = zx[(size_t)t * DPROJ + 4224 + hh] + dtb[hh];
    float sp = raw > 20.f ? raw : log1pf(expf(raw));
    dtsp[t * 32 + hh] = sp;
    dag[t * 32 + hh] = expf(-expf(alog[hh]) * sp);
  }
}

// ---------------------------------------------------------------- chunked scan
__global__ __launch_bounds__(256) void k_scan_local(
    const float* __restrict__ xbc, const float* __restrict__ dtsp,
    const float* __restrict__ dag, float* __restrict__ yb, float* __restrict__ Sloc,
    float* __restrict__ pref, float* __restrict__ dacum)
{
  int c = blockIdx.x, hh = blockIdx.y;
  int tid = threadIdx.x;
  int p = tid >> 2, ng = tid & 3, n0 = ng << 4;
  float st[16];
#pragma unroll
  for (int j = 0; j < 16; ++j) st[j] = 0.f;
  float P = 1.f;
  for (int s_ = 0; s_ < CLEN; ++s_) {
    int t = c * CLEN + s_;
    float dA = dag[t * 32 + hh];
    P *= dA;
    if (tid == 0) pref[t * 32 + hh] = P;
    float coef = dtsp[t * 32 + hh] * xbc[(size_t)t * CONVDIM + hh * 64 + p];
    const f32x4* B4 = (const f32x4*)&xbc[(size_t)t * CONVDIM + 2048 + n0];
    const f32x4* C4 = (const f32x4*)&xbc[(size_t)t * CONVDIM + 2112 + n0];
    float y = 0.f;
#pragma unroll
    for (int q = 0; q < 4; ++q) {
      f32x4 b = B4[q], cc = C4[q];
#pragma unroll
      for (int e = 0; e < 4; ++e) {
        int j = q * 4 + e;
        st[j] = dA * st[j] + coef * b[e];
        y += st[j] * cc[e];
      }
    }
    y += __shfl_xor(y, 1);
    y += __shfl_xor(y, 2);
    if (ng == 0) yb[(size_t)t * DINNER + hh * 64 + p] = y;
  }
  if (tid == 0) dacum[c * 32 + hh] = P;
  float* Sp = Sloc + ((size_t)(c * 32 + hh) * 64 + p) * 64 + n0;
#pragma unroll
  for (int q = 0; q < 4; ++q)
    *(f32x4*)(Sp + q * 4) = (f32x4){ st[q*4], st[q*4+1], st[q*4+2], st[q*4+3] };
}

__global__ void k_chain(const float* __restrict__ Sloc, const float* __restrict__ dacum,
                        float* __restrict__ Sin) {
  int e = blockIdx.x * 256 + threadIdx.x;  // 131072
  int hh = e >> 12;
  float S = 0.f;
  for (int c = 0; c < NCHUNK; c += 8) {
    float sl[8], dd[8];
#pragma unroll
    for (int j = 0; j < 8; ++j) sl[j] = Sloc[(size_t)(c + j) * 131072 + e];
#pragma unroll
    for (int j = 0; j < 8; ++j) dd[j] = dacum[(c + j) * 32 + hh];
#pragma unroll
    for (int j = 0; j < 8; ++j) {
      Sin[(size_t)(c + j) * 131072 + e] = S;
      S = dd[j] * S + sl[j];
    }
  }
}

__global__ __launch_bounds__(256) void k_scan_fix(
    const float* __restrict__ xbc, const float* __restrict__ pref,
    const float* __restrict__ Sin, const float* __restrict__ Dp,
    float* __restrict__ yb)
{
  __shared__ float Sl[64 * 68];
  int c = blockIdx.x, hh = blockIdx.y;
  int tid = threadIdx.x;
  for (int i = 0; i < 16; ++i) {
    int e = i * 256 + tid;
    Sl[(e >> 6) * 68 + (e & 63)] = Sin[(size_t)(c * 32 + hh) * 4096 + e];
  }
  __syncthreads();
  int p = tid >> 2, ng = tid & 3, n0 = ng << 4;
  float Dh = Dp[hh];
  for (int s_ = 0; s_ < CLEN; ++s_) {
    int t = c * CLEN + s_;
    const f32x4* C4 = (const f32x4*)&xbc[(size_t)t * CONVDIM + 2112 + n0];
    float yc = 0.f;
#pragma unroll
    for (int q = 0; q < 4; ++q) {
      f32x4 cc = C4[q];
#pragma unroll
      for (int e = 0; e < 4; ++e) yc += Sl[p * 68 + n0 + q * 4 + e] * cc[e];
    }
    yc += __shfl_xor(yc, 1);
    yc += __shfl_xor(yc, 2);
    if (ng == 0) {
      size_t oy = (size_t)t * DINNER + hh * 64 + p;
      yb[oy] = yb[oy] + pref[t * 32 + hh] * yc + Dh * xbc[(size_t)t * CONVDIM + hh * 64 + p];
    }
  }
}

__global__ void k_gated_rms(const float* __restrict__ yb, const float* __restrict__ zx,
                            const float* __restrict__ gw, u16* __restrict__ out) {
  int t = blockIdx.x, tid = threadIdx.x;
  float v[8], ss = 0.f;
#pragma unroll
  for (int i = 0; i < 8; ++i) {
    int j = tid + i * 256;
    float z = zx[(size_t)t * DPROJ + j];
    float vv = yb[(size_t)t * DINNER + j] * silu_f(z);
    v[i] = vv; ss += vv * vv;
  }
#pragma unroll
  for (int o = 32; o; o >>= 1) ss += __shfl_down(ss, o);
  __shared__ float sb[4];
  if ((tid & 63) == 0) sb[tid >> 6] = ss;
  __syncthreads();
  ss = sb[0] + sb[1] + sb[2] + sb[3];
  float rstd = rsqrtf(ss * (1.f / 2048.f) + 1e-5f);
#pragma unroll
  for (int i = 0; i < 8; ++i) {
    int j = tid + i * 256;
    out[(size_t)t * DINNER + j] = f2bf(v[i] * rstd * gw[j]);
  }
}

// ---------------------------------------------------------------- loss
__global__ void k_loss_final(const float* __restrict__ lsepart,
                             const float* __restrict__ logits,
                             const int* __restrict__ tgt, float* __restrict__ part) {
  int t = blockIdx.x, tid = threadIdx.x;
  float m = -1e30f, s = 0.f;
  for (int nb = tid; nb < NBLK_V; nb += 256) {
    f32x2 v = ((const f32x2*)lsepart)[(size_t)t * NBLK_V + nb];
    float M = fmaxf(m, v[0]);
    s = s * expf(m - M) + v[1] * expf(v[0] - M);
    m = M;
  }
#pragma unroll
  for (int o = 32; o; o >>= 1) {
    float m2 = __shfl_down(m, o), s2 = __shfl_down(s, o);
    float M = fmaxf(m, m2);
    s = s * expf(m - M) + s2 * expf(m2 - M);
    m = M;
  }
  __shared__ float ms[4], ssh[4];
  if ((tid & 63) == 0) { ms[tid >> 6] = m; ssh[tid >> 6] = s; }
  __syncthreads();
  if (tid == 0) {
    float M = ms[0], S = ssh[0];
    for (int w = 1; w < 4; ++w) {
      float M2 = fmaxf(M, ms[w]);
      S = S * expf(M - M2) + ssh[w] * expf(ms[w] - M2);
      M = M2;
    }
    part[t] = (M + logf(S)) - logits[(size_t)t * VOCAB + tgt[t]];
  }
}

__global__ void k_loss_mean(const float* __restrict__ part, float* __restrict__ out) {
  int tid = threadIdx.x;
  float s = 0.f;
  for (int j = tid; j < 1024; j += 256) s += part[j];
#pragma unroll
  for (int o = 32; o; o >>= 1) s += __shfl_down(s, o);
  __shared__ float sb[4];
  if ((tid & 63) == 0) sb[tid >> 6] = s;
  __syncthreads();
  if (tid == 0) out[0] = (sb[0] + sb[1] + sb[2] + sb[3]) * (1.f / 1024.f);
}

// ---------------------------------------------------------------- launch
extern "C" void kernel_launch(void* const* d_in, const int* in_sizes, int n_in,
                              void* d_out, int out_size, void* d_ws, size_t ws_size,
                              hipStream_t stream)
{
  const int*   idx       = (const int*)d_in[0];
  const int*   tgt       = (const int*)d_in[1];
  const float* E         = (const float*)d_in[2];
  const float* norm_w    = (const float*)d_in[3];
  const float* norm2_w   = (const float*)d_in[4];
  const float* in_proj_w = (const float*)d_in[5];
  const float* conv_w    = (const float*)d_in[6];
  const float* conv_b    = (const float*)d_in[7];
  const float* dt_bias   = (const float*)d_in[8];
  const float* A_log     = (const float*)d_in[9];
  const float* Dp        = (const float*)d_in[10];
  const float* gnorm_w   = (const float*)d_in[11];
  const float* out_proj_w= (const float*)d_in[12];
  const float* fc1_w     = (const float*)d_in[13];
  const float* fc2_w     = (const float*)d_in[14];
  const float* norm_f_w  = (const float*)d_in[15];
  float* logits = (float*)d_out;
  (void)in_sizes; (void)n_in; (void)out_size; (void)ws_size;

  char* W = (char*)d_ws;
  size_t off = 0;
  auto A8 = [&](size_t bytes) { void* p = W + off; off = (off + bytes + 255) & ~(size_t)255; return p; };
  float* hbuf   = (float*)A8((size_t)1024 * 1024 * 4);
  u16*   xnormb = (u16*)  A8((size_t)1024 * 1024 * 2);
  u16*   gatedb = (u16*)  A8((size_t)1024 * 2048 * 2);
  u16*   glub   = (u16*)  A8((size_t)1024 * 4096 * 2);
  float* dtsp   = (float*)A8((size_t)1024 * 32 * 4);
  float* dag    = (float*)A8((size_t)1024 * 32 * 4);
  float* pref   = (float*)A8((size_t)1024 * 32 * 4);
  float* dacum  = (float*)A8((size_t)2048 * 4);
  float* lpart  = (float*)A8((size_t)1024 * 4);
  float* lsebuf = (float*)A8((size_t)1024 * NBLK_V * 2 * 4);
  u16*   wip    = (u16*)  A8((size_t)2 * 4352 * 1024 * 2);
  u16*   wop    = (u16*)  A8((size_t)2 * 1024 * 2048 * 2);
  u16*   wfc1   = (u16*)  A8((size_t)2 * 8192 * 1024 * 2);
  u16*   wfc2   = (u16*)  A8((size_t)2 * 1024 * 4096 * 2);
  // shared span: layer temporaries; Ebf aliases it after layers are done
  char*  span   = (char*)A8((size_t)117964800);
  float* big0   = (float*)(span);                          // 17.4 MB (1024x4256)
  float* xbc    = (float*)(span + 33554432);               // 8.9 MB
  float* yb     = (float*)(span + 33554432 + 8912896);     // 8 MB
  float* Sloc   = (float*)(span + 33554432 + 8912896 + 8388608);
  float* Sin    = (float*)((char*)Sloc + 33554432);
  float* part   = Sloc;                                    // splitK slices alias
  u16*   Ebf    = (u16*)span;                              // 100 MB alias (51200x1024)

  dim3 b256(256), b512(512);

  k_cvt8_pad<<<dim3((4352*1024/8 + 255)/256), b256, 0, stream>>>(
      in_proj_w, wip, 4352*1024/8, 4256*1024/8);
  k_cvt8_pad<<<dim3((4352*1024/8 + 255)/256), b256, 0, stream>>>(
      in_proj_w + (size_t)4256*1024, wip + (size_t)4352*1024, 4352*1024/8, 4256*1024/8);
  k_cvt8<<<dim3(2*1024*2048/8/256), b256, 0, stream>>>(out_proj_w, wop, 2*1024*2048/8);
  k_cvt_fc1<<<dim3(2*8192*1024/8/256), b256, 0, stream>>>(fc1_w, wfc1, 2*8192*1024/8);
  k_cvt8<<<dim3(2*1024*4096/8/256), b256, 0, stream>>>(fc2_w, wfc2, 2*1024*4096/8);

  k_ln_embed<<<1024, b256, 0, stream>>>(idx, E, norm_w, hbuf, xnormb);

  const float* nw_next[2] = { norm_w + 1024, norm_f_w };
  for (int L = 0; L < 2; ++L) {
    gemm_bf16<<<dim3(8, 34, 1), b256, 0, stream>>>(
        xnormb, wip + (size_t)L * 4352 * 1024, big0, DPROJ, 1024, 1024);
    k_convdt<<<dim3(9, 1024), b256, 0, stream>>>(
        big0, conv_w + L * CONVDIM * 4, conv_b + L * CONVDIM,
        dt_bias + L * 32, A_log + L * 32, xbc, dtsp, dag);
    k_scan_local<<<dim3(NCHUNK, 32), b256, 0, stream>>>(xbc, dtsp, dag, yb, Sloc, pref, dacum);
    k_chain<<<512, b256, 0, stream>>>(Sloc, dacum, Sin);
    k_scan_fix<<<dim3(NCHUNK, 32), b256, 0, stream>>>(xbc, pref, Sin, Dp + L * 32, yb);
    k_gated_rms<<<1024, b256, 0, stream>>>(yb, big0, gnorm_w + L * 2048, gatedb);
    gemm_bf16<<<dim3(8, 8, 4), b256, 0, stream>>>(
        gatedb, wop + (size_t)L * 1024 * 2048, part, 1024, 2048, 512);
    k_red_ln<<<1024, b256, 0, stream>>>(part, 4, hbuf, norm2_w + L * 1024, xnormb);
    gemm256<<<dim3(4, 64, 1), b512, 0, stream>>>(
        xnormb, wfc1 + (size_t)L * 8192 * 1024, glub, 8192, 1024);
    gemm_bf16<<<dim3(8, 8, 8), b256, 0, stream>>>(
        glub, wfc2 + (size_t)L * 1024 * 4096, part, 1024, 4096, 512);
    k_red_ln<<<1024, b256, 0, stream>>>(part, 8, hbuf, nw_next[L], xnormb);
  }

  k_cvt8_pad<<<dim3((VOCABP*1024/8 + 255)/256), b256, 0, stream>>>(
      E, Ebf, VOCABP*1024/8, VOCAB*1024/8);
  gemm_lm<<<dim3(4 * NBLK_V, 1, 1), b512, 0, stream>>>(
      xnormb, Ebf, logits, VOCAB, 1024, lsebuf);
  k_loss_final<<<1024, b256, 0, stream>>>(lsebuf, logits, tgt, lpart);
  k_loss_mean<<<1, b256, 0, stream>>>(lpart, logits + (size_t)1024 * VOCAB);
}

// Round 12
// 790.638 us; speedup vs baseline: 1.2196x; 1.2196x over previous
//
#include <hip/hip_runtime.h>
#include <cmath>

#define DMODEL  1024
#define DINNER  2048
#define NHEADS  32
#define CONVDIM 2176
#define DPROJ   4256
#define VOCAB   50257
#define NBLK_V  400            // LM-head n-blocks (padded: 400*128 = 51200 rows)
#define VOCABP  (NBLK_V * 128)
#define CLEN    32
#define NCHUNK  32

typedef float f32x4 __attribute__((ext_vector_type(4)));
typedef float f32x2 __attribute__((ext_vector_type(2)));
typedef unsigned short u16;
typedef u16 u16x4 __attribute__((ext_vector_type(4)));
typedef u16 u16x8 __attribute__((ext_vector_type(8)));
typedef __bf16 bf16x8 __attribute__((ext_vector_type(8)));

__device__ __forceinline__ u16 f2bf(float f) {
  unsigned u = __builtin_bit_cast(unsigned, f);
  u += 0x7FFFu + ((u >> 16) & 1u);
  return (u16)(u >> 16);
}
__device__ __forceinline__ float silu_f(float x) { return x / (1.f + expf(-x)); }

__device__ __forceinline__ void gload16(const u16* g, u16* l) {
  __builtin_amdgcn_global_load_lds(
      (const __attribute__((address_space(1))) void*)g,
      (__attribute__((address_space(3))) void*)l,
      16, 0, 0);
}
__device__ __forceinline__ void vm_wait0() { asm volatile("s_waitcnt vmcnt(0)" ::: "memory"); }

// ---------------------------------------------------------------- 128x128 GEMM
// R7-proven: 4 waves, BK=32, 3-deep LDS, counted vmcnt(4); bf16 A and B.
// Swizzle: 64B rows, phys chunk = data ^ ((row>>1)&3); conflict-free.
__global__ __launch_bounds__(256) void gemm_bf16(
    const u16* __restrict__ A, const u16* __restrict__ B,
    float* __restrict__ C, int N, int K, int kslice)
{
  __shared__ alignas(128) u16 As[3 * 4096];
  __shared__ alignas(128) u16 Bs[3 * 4096];
  const int tid = threadIdx.x;
  const int m0 = blockIdx.x << 7;
  const int n0 = blockIdx.y << 7;
  const int lane = tid & 63, wid = tid >> 6;
  const int wm = (wid >> 1) << 6, wn = (wid & 1) << 6;
  const int lr = lane & 15, kg = lane >> 4;

  const int srow = wid * 16 + (lane >> 2);
  const int scol = ((lane & 3) ^ ((lane >> 3) & 3)) << 3;
  const u16* gA = A + (size_t)(m0 + srow) * K + scol;
  const u16* gB = B + (size_t)(n0 + srow) * K + scol;

  f32x4 acc[4][4];
#pragma unroll
  for (int i = 0; i < 4; ++i)
#pragma unroll
    for (int j = 0; j < 4; ++j) acc[i][j] = (f32x4){0.f, 0.f, 0.f, 0.f};

  const int kb = blockIdx.z * kslice;
  const int nt = kslice >> 5;

  auto stage = [&](int buf, int t) {
    const int ko = kb + (t << 5);
#pragma unroll
    for (int i = 0; i < 2; ++i) {
      gload16(gA + ko + (size_t)i * 64 * K, &As[buf * 4096 + i * 2048 + wid * 512]);
      gload16(gB + ko + (size_t)i * 64 * K, &Bs[buf * 4096 + i * 2048 + wid * 512]);
    }
  };

  stage(0, 0);
  stage(1, 1);
  int b0 = 0, b1 = 1, b2 = 2;
  const int cxr = (lr >> 1) & 3;
  for (int t = 0; t < nt; ++t) {
    if (t == nt - 1) vm_wait0();
    else             asm volatile("s_waitcnt vmcnt(4)" ::: "memory");
    __builtin_amdgcn_s_barrier();
    if (t + 2 < nt) stage(b2, t + 2);
    bf16x8 af[4], bfr[4];
    const int po = (kg ^ cxr) << 3;
#pragma unroll
    for (int f = 0; f < 4; ++f) {
      af[f]  = *(const bf16x8*)&As[b0 * 4096 + (wm + f * 16 + lr) * 32 + po];
      bfr[f] = *(const bf16x8*)&Bs[b0 * 4096 + (wn + f * 16 + lr) * 32 + po];
    }
#pragma unroll
    for (int i = 0; i < 4; ++i)
#pragma unroll
      for (int j = 0; j < 4; ++j)
        acc[i][j] = __builtin_amdgcn_mfma_f32_16x16x32_bf16(af[i], bfr[j], acc[i][j], 0, 0, 0);
    int tmp = b0; b0 = b1; b1 = b2; b2 = tmp;
  }

  const int mr = (lane >> 4) << 2;
  const int nc = lane & 15;
  float* Cw = C + (gridDim.z > 1 ? (size_t)blockIdx.z * 1024 * N : 0);
#pragma unroll
  for (int i = 0; i < 4; ++i)
#pragma unroll
    for (int j = 0; j < 4; ++j) {
      int n = n0 + wn + j * 16 + nc;
      if (n < N) {
#pragma unroll
        for (int e = 0; e < 4; ++e)
          Cw[(size_t)(m0 + wm + i * 16 + mr + e) * N + n] = acc[i][j][e];
      }
    }
}

// ---------------------------------------------------------------- 256x128 GEMM
// R7-proven: 8 waves, BK=32, 3-deep, counted vmcnt(3).
// swz=1 (LM head): 1-D grid 4m x 400n XCD-bijective; lsepart LSE partials.
// glu_out: fc1 fusion (interleaved y/g rows; epilogue emits bf16 y*silu(g)).
__global__ __launch_bounds__(512) void gemm256(
    const u16* __restrict__ A, const u16* __restrict__ B,
    float* __restrict__ C, int N, int K,
    float* __restrict__ lsepart, int swz, int nblk,
    u16* __restrict__ glu_out)
{
  __shared__ alignas(128) u16 As[3 * 8192];   // 3 x 256x32
  __shared__ alignas(128) u16 Bs[3 * 4096];   // 3 x 128x32
  const int tid = threadIdx.x;
  int m0, n0;
  if (swz) {
    int bid = blockIdx.x;
    m0 = ((bid >> 3) & 3) << 8;
    n0 = ((bid & 7) + ((bid >> 5) << 3)) << 7;
  } else {
    m0 = blockIdx.x << 8;
    n0 = blockIdx.y << 7;
  }
  const int lane = tid & 63, wid = tid >> 6;       // 8 waves
  const int wm = (wid >> 1) << 6, wn = (wid & 1) << 6;
  const int lr = lane & 15, kg = lane >> 4;

  const int srow = wid * 16 + (lane >> 2);         // 128 rows per issue
  const int scol = ((lane & 3) ^ ((lane >> 3) & 3)) << 3;
  const u16* gA = A + (size_t)(m0 + srow) * K + scol;
  const u16* gB = B + (size_t)(n0 + srow) * K + scol;

  f32x4 acc[4][4];
#pragma unroll
  for (int i = 0; i < 4; ++i)
#pragma unroll
    for (int j = 0; j < 4; ++j) acc[i][j] = (f32x4){0.f, 0.f, 0.f, 0.f};

  const int nt = K >> 5;

  auto stage = [&](int buf, int t) {
    const int ko = t << 5;
    gload16(gA + ko,                     &As[buf * 8192 + wid * 512]);
    gload16(gA + ko + (size_t)128 * K,   &As[buf * 8192 + 4096 + wid * 512]);
    gload16(gB + ko,                     &Bs[buf * 4096 + wid * 512]);
  };

  stage(0, 0);
  stage(1, 1);
  int b0 = 0, b1 = 1, b2 = 2;
  const int cxr = (lr >> 1) & 3;
  for (int t = 0; t < nt; ++t) {
    if (t == nt - 1) vm_wait0();
    else             asm volatile("s_waitcnt vmcnt(3)" ::: "memory");
    __builtin_amdgcn_s_barrier();
    if (t + 2 < nt) stage(b2, t + 2);
    bf16x8 af[4], bfr[4];
    const int po = (kg ^ cxr) << 3;
#pragma unroll
    for (int f = 0; f < 4; ++f) {
      af[f]  = *(const bf16x8*)&As[b0 * 8192 + (wm + f * 16 + lr) * 32 + po];
      bfr[f] = *(const bf16x8*)&Bs[b0 * 4096 + (wn + f * 16 + lr) * 32 + po];
    }
#pragma unroll
    for (int i = 0; i < 4; ++i)
#pragma unroll
      for (int j = 0; j < 4; ++j)
        acc[i][j] = __builtin_amdgcn_mfma_f32_16x16x32_bf16(af[i], bfr[j], acc[i][j], 0, 0, 0);
    int tmp = b0; b0 = b1; b1 = b2; b2 = tmp;
  }

  const int mr = (lane >> 4) << 2;
  const int nc = lane & 15;

  if (glu_out) {
#pragma unroll
    for (int i = 0; i < 4; ++i)
#pragma unroll
      for (int j = 0; j < 4; ++j)
#pragma unroll
        for (int e = 0; e < 4; ++e) {
          float v = acc[i][j][e];
          float p = __shfl_xor(v, 1);
          if (!(nc & 1)) {
            int q = (n0 + wn + j * 16 + nc) >> 1;
            int row = m0 + wm + i * 16 + mr + e;
            glu_out[(size_t)row * 4096 + q] = f2bf(v * silu_f(p));
          }
        }
    return;
  }

#pragma unroll
  for (int i = 0; i < 4; ++i)
#pragma unroll
    for (int j = 0; j < 4; ++j) {
      int n = n0 + wn + j * 16 + nc;
      if (n < N) {
#pragma unroll
        for (int e = 0; e < 4; ++e)
          C[(size_t)(m0 + wm + i * 16 + mr + e) * N + n] = acc[i][j][e];
      }
    }

  if (lsepart) {
    __syncthreads();
    float* Ls = (float*)As;    // [256 rows][2 halves][2] = 4KB
#pragma unroll
    for (int i = 0; i < 4; ++i)
#pragma unroll
      for (int e = 0; e < 4; ++e) {
        float pm = -1e30f;
#pragma unroll
        for (int j = 0; j < 4; ++j) {
          int n = n0 + wn + j * 16 + nc;
          if (n < N) pm = fmaxf(pm, acc[i][j][e]);
        }
#pragma unroll
        for (int o = 1; o < 16; o <<= 1) pm = fmaxf(pm, __shfl_xor(pm, o));
        float ps = 0.f;
#pragma unroll
        for (int j = 0; j < 4; ++j) {
          int n = n0 + wn + j * 16 + nc;
          if (n < N) ps += expf(acc[i][j][e] - pm);
        }
#pragma unroll
        for (int o = 1; o < 16; o <<= 1) ps += __shfl_xor(ps, o);
        if (nc == 0) {
          int row = wm + i * 16 + mr + e;
          Ls[row * 4 + (wid & 1) * 2] = pm;
          Ls[row * 4 + (wid & 1) * 2 + 1] = ps;
        }
      }
    __syncthreads();
    if (tid < 256) {
      float pa = Ls[tid * 4], sa = Ls[tid * 4 + 1];
      float pb = Ls[tid * 4 + 2], sb = Ls[tid * 4 + 3];
      float M = fmaxf(pa, pb);
      float S = sa * expf(pa - M) + sb * expf(pb - M);
      ((f32x2*)lsepart)[(size_t)(m0 + tid) * nblk + (n0 >> 7)] = (f32x2){M, S};
    }
  }
}

// ---------------------------------------------------------------- conversions
__global__ void k_cvt8(const float* __restrict__ src, u16* __restrict__ dst, int n8) {
  int i = blockIdx.x * 256 + threadIdx.x;
  if (i >= n8) return;
  f32x4 a = ((const f32x4*)src)[i * 2];
  f32x4 b = ((const f32x4*)src)[i * 2 + 1];
  u16x8 o = { f2bf(a[0]), f2bf(a[1]), f2bf(a[2]), f2bf(a[3]),
              f2bf(b[0]), f2bf(b[1]), f2bf(b[2]), f2bf(b[3]) };
  ((u16x8*)dst)[i] = o;
}

__global__ void k_cvt8_pad(const float* __restrict__ src, u16* __restrict__ dst,
                           int n8, int srcN8) {
  int i = blockIdx.x * 256 + threadIdx.x;
  if (i >= n8) return;
  u16x8 o;
  if (i < srcN8) {
    f32x4 a = ((const f32x4*)src)[i * 2];
    f32x4 b = ((const f32x4*)src)[i * 2 + 1];
    o = (u16x8){ f2bf(a[0]), f2bf(a[1]), f2bf(a[2]), f2bf(a[3]),
                 f2bf(b[0]), f2bf(b[1]), f2bf(b[2]), f2bf(b[3]) };
  } else {
    o = (u16x8){0, 0, 0, 0, 0, 0, 0, 0};
  }
  ((u16x8*)dst)[i] = o;
}

// fc1 weights with y/g row interleave
__global__ void k_cvt_fc1(const float* __restrict__ src, u16* __restrict__ dst, int n8) {
  int i = blockIdx.x * 256 + threadIdx.x;
  if (i >= n8) return;  // n8 = 2*8192*128
  f32x4 a = ((const f32x4*)src)[i * 2];
  f32x4 b = ((const f32x4*)src)[i * 2 + 1];
  u16x8 o = { f2bf(a[0]), f2bf(a[1]), f2bf(a[2]), f2bf(a[3]),
              f2bf(b[0]), f2bf(b[1]), f2bf(b[2]), f2bf(b[3]) };
  int R = i >> 7, col8 = i & 127;
  int layer = R >> 13, r = R & 8191;
  int dstr = (r < 4096) ? (r << 1) : (((r - 4096) << 1) | 1);
  ((u16x8*)dst)[((size_t)(layer << 13) + dstr) * 128 + col8] = o;
}

// ---------------------------------------------------------------- fused LN
__device__ __forceinline__ void ln_write(f32x4 v, const float* __restrict__ w,
                                         u16* __restrict__ out, int t, int tid) {
  float s = v[0] + v[1] + v[2] + v[3];
  float sq = v[0]*v[0] + v[1]*v[1] + v[2]*v[2] + v[3]*v[3];
#pragma unroll
  for (int o = 32; o; o >>= 1) { s += __shfl_down(s, o); sq += __shfl_down(sq, o); }
  __shared__ float sb[4], qb[4];
  if ((tid & 63) == 0) { sb[tid >> 6] = s; qb[tid >> 6] = sq; }
  __syncthreads();
  s = sb[0] + sb[1] + sb[2] + sb[3];
  sq = qb[0] + qb[1] + qb[2] + qb[3];
  float mu = s * (1.f / 1024.f);
  float rstd = rsqrtf(sq * (1.f / 1024.f) - mu * mu + 1e-5f);
  u16x4 o;
#pragma unroll
  for (int e = 0; e < 4; ++e) o[e] = f2bf((v[e] - mu) * rstd * w[tid * 4 + e]);
  ((u16x4*)out)[t * 256 + tid] = o;
}

__global__ void k_ln_embed(const int* __restrict__ idx, const float* __restrict__ E,
                           const float* __restrict__ w, float* __restrict__ hbuf,
                           u16* __restrict__ out) {
  int t = blockIdx.x, tid = threadIdx.x;
  f32x4 v = ((const f32x4*)(E + (size_t)idx[t] * DMODEL))[tid];
  ((f32x4*)hbuf)[t * 256 + tid] = v;
  ln_write(v, w, out, t, tid);
}

__global__ void k_red_ln(const float* __restrict__ part, int S,
                         float* __restrict__ hbuf, const float* __restrict__ w,
                         u16* __restrict__ out) {
  int t = blockIdx.x, tid = threadIdx.x;
  f32x4 v = ((const f32x4*)hbuf)[t * 256 + tid];
  for (int k = 0; k < S; ++k)
    v += ((const f32x4*)part)[(size_t)k * 262144 + t * 256 + tid];
  ((f32x4*)hbuf)[t * 256 + tid] = v;
  ln_write(v, w, out, t, tid);
}

// ---------------------------------------------------------------- conv + dt
__global__ void k_convdt(const float* __restrict__ zx, const float* __restrict__ cw,
                         const float* __restrict__ cb, const float* __restrict__ dtb,
                         const float* __restrict__ alog, float* __restrict__ xbc,
                         float* __restrict__ dtsp, float* __restrict__ dag) {
  int t = blockIdx.y, x = blockIdx.x, tid = threadIdx.x;
  if (x < 8 || tid < 128) {
    int c = x * 256 + tid;
    float acc = cb[c];
#pragma unroll
    for (int k = 0; k < 4; ++k) {
      int tt = t + k - 3;
      if (tt >= 0) acc += zx[(size_t)tt * DPROJ + 2048 + c] * cw[c * 4 + k];
    }
    xbc[(size_t)t * CONVDIM + c] = silu_f(acc);
  } else if (tid < 160) {
    int hh = tid - 128;
    float raw = zx[(size_t)t * DPROJ + 4224 + hh] + dtb[hh];
    float sp = raw > 20.f ? raw : log1pf(expf(raw));
    dtsp[t * 32 + hh] = sp;
    dag[t * 32 + hh] = expf(-expf(alog[hh]) * sp);
  }
}

// ---------------------------------------------------------------- chunked scan
__global__ __launch_bounds__(256) void k_scan_local(
    const float* __restrict__ xbc, const float* __restrict__ dtsp,
    const float* __restrict__ dag, float* __restrict__ yb, float* __restrict__ Sloc,
    float* __restrict__ pref, float* __restrict__ dacum)
{
  int c = blockIdx.x, hh = blockIdx.y;
  int tid = threadIdx.x;
  int p = tid >> 2, ng = tid & 3, n0 = ng << 4;
  float st[16];
#pragma unroll
  for (int j = 0; j < 16; ++j) st[j] = 0.f;
  float P = 1.f;
  for (int s_ = 0; s_ < CLEN; ++s_) {
    int t = c * CLEN + s_;
    float dA = dag[t * 32 + hh];
    P *= dA;
    if (tid == 0) pref[t * 32 + hh] = P;
    float coef = dtsp[t * 32 + hh] * xbc[(size_t)t * CONVDIM + hh * 64 + p];
    const f32x4* B4 = (const f32x4*)&xbc[(size_t)t * CONVDIM + 2048 + n0];
    const f32x4* C4 = (const f32x4*)&xbc[(size_t)t * CONVDIM + 2112 + n0];
    float y = 0.f;
#pragma unroll
    for (int q = 0; q < 4; ++q) {
      f32x4 b = B4[q], cc = C4[q];
#pragma unroll
      for (int e = 0; e < 4; ++e) {
        int j = q * 4 + e;
        st[j] = dA * st[j] + coef * b[e];
        y += st[j] * cc[e];
      }
    }
    y += __shfl_xor(y, 1);
    y += __shfl_xor(y, 2);
    if (ng == 0) yb[(size_t)t * DINNER + hh * 64 + p] = y;
  }
  if (tid == 0) dacum[c * 32 + hh] = P;
  float* Sp = Sloc + ((size_t)(c * 32 + hh) * 64 + p) * 64 + n0;
#pragma unroll
  for (int q = 0; q < 4; ++q)
    *(f32x4*)(Sp + q * 4) = (f32x4){ st[q*4], st[q*4+1], st[q*4+2], st[q*4+3] };
}

__global__ void k_chain(const float* __restrict__ Sloc, const float* __restrict__ dacum,
                        float* __restrict__ Sin) {
  int e = blockIdx.x * 256 + threadIdx.x;  // 131072
  int hh = e >> 12;
  float S = 0.f;
  for (int c = 0; c < NCHUNK; c += 8) {
    float sl[8], dd[8];
#pragma unroll
    for (int j = 0; j < 8; ++j) sl[j] = Sloc[(size_t)(c + j) * 131072 + e];
#pragma unroll
    for (int j = 0; j < 8; ++j) dd[j] = dacum[(c + j) * 32 + hh];
#pragma unroll
    for (int j = 0; j < 8; ++j) {
      Sin[(size_t)(c + j) * 131072 + e] = S;
      S = dd[j] * S + sl[j];
    }
  }
}

__global__ __launch_bounds__(256) void k_scan_fix(
    const float* __restrict__ xbc, const float* __restrict__ pref,
    const float* __restrict__ Sin, const float* __restrict__ Dp,
    float* __restrict__ yb)
{
  __shared__ float Sl[64 * 68];
  int c = blockIdx.x, hh = blockIdx.y;
  int tid = threadIdx.x;
  for (int i = 0; i < 16; ++i) {
    int e = i * 256 + tid;
    Sl[(e >> 6) * 68 + (e & 63)] = Sin[(size_t)(c * 32 + hh) * 4096 + e];
  }
  __syncthreads();
  int p = tid >> 2, ng = tid & 3, n0 = ng << 4;
  float Dh = Dp[hh];
  for (int s_ = 0; s_ < CLEN; ++s_) {
    int t = c * CLEN + s_;
    const f32x4* C4 = (const f32x4*)&xbc[(size_t)t * CONVDIM + 2112 + n0];
    float yc = 0.f;
#pragma unroll
    for (int q = 0; q < 4; ++q) {
      f32x4 cc = C4[q];
#pragma unroll
      for (int e = 0; e < 4; ++e) yc += Sl[p * 68 + n0 + q * 4 + e] * cc[e];
    }
    yc += __shfl_xor(yc, 1);
    yc += __shfl_xor(yc, 2);
    if (ng == 0) {
      size_t oy = (size_t)t * DINNER + hh * 64 + p;
      yb[oy] = yb[oy] + pref[t * 32 + hh] * yc + Dh * xbc[(size_t)t * CONVDIM + hh * 64 + p];
    }
  }
}

__global__ void k_gated_rms(const float* __restrict__ yb, const float* __restrict__ zx,
                            const float* __restrict__ gw, u16* __restrict__ out) {
  int t = blockIdx.x, tid = threadIdx.x;
  float v[8], ss = 0.f;
#pragma unroll
  for (int i = 0; i < 8; ++i) {
    int j = tid + i * 256;
    float z = zx[(size_t)t * DPROJ + j];
    float vv = yb[(size_t)t * DINNER + j] * silu_f(z);
    v[i] = vv; ss += vv * vv;
  }
#pragma unroll
  for (int o = 32; o; o >>= 1) ss += __shfl_down(ss, o);
  __shared__ float sb[4];
  if ((tid & 63) == 0) sb[tid >> 6] = ss;
  __syncthreads();
  ss = sb[0] + sb[1] + sb[2] + sb[3];
  float rstd = rsqrtf(ss * (1.f / 2048.f) + 1e-5f);
#pragma unroll
  for (int i = 0; i < 8; ++i) {
    int j = tid + i * 256;
    out[(size_t)t * DINNER + j] = f2bf(v[i] * rstd * gw[j]);
  }
}

// ---------------------------------------------------------------- loss (fused)
// blocks 0..1023: per-row LSE from partials -> part[t]; last block also
// cannot reduce (no grid sync), so the mean runs in a 1-block pass below
// fused via atomic-free two-kernel-in-one trick is unsafe -> keep a tiny
// second launch? Instead: block t computes part[t]; block 1024 (extra)
// cannot see others' results. So: fold mean into k_loss_final by having
// block 0 re-read part[] is racy. We keep the mean in the SAME kernel by
// launching 1025 blocks and making block 1024 spin? Forbidden (no order
// guarantees). => single safe fusion: compute part[t] here, mean kernel
// stays (it is ~3 us). Net: unchanged proven path.
__global__ void k_loss_final(const float* __restrict__ lsepart,
                             const float* __restrict__ logits,
                             const int* __restrict__ tgt, float* __restrict__ part) {
  int t = blockIdx.x, tid = threadIdx.x;
  float m = -1e30f, s = 0.f;
  for (int nb = tid; nb < NBLK_V; nb += 256) {
    f32x2 v = ((const f32x2*)lsepart)[(size_t)t * NBLK_V + nb];
    float M = fmaxf(m, v[0]);
    s = s * expf(m - M) + v[1] * expf(v[0] - M);
    m = M;
  }
#pragma unroll
  for (int o = 32; o; o >>= 1) {
    float m2 = __shfl_down(m, o), s2 = __shfl_down(s, o);
    float M = fmaxf(m, m2);
    s = s * expf(m - M) + s2 * expf(m2 - M);
    m = M;
  }
  __shared__ float ms[4], ssh[4];
  if ((tid & 63) == 0) { ms[tid >> 6] = m; ssh[tid >> 6] = s; }
  __syncthreads();
  if (tid == 0) {
    float M = ms[0], S = ssh[0];
    for (int w = 1; w < 4; ++w) {
      float M2 = fmaxf(M, ms[w]);
      S = S * expf(M - M2) + ssh[w] * expf(ms[w] - M2);
      M = M2;
    }
    part[t] = (M + logf(S)) - logits[(size_t)t * VOCAB + tgt[t]];
  }
}

__global__ void k_loss_mean(const float* __restrict__ part, float* __restrict__ out) {
  int tid = threadIdx.x;
  float s = 0.f;
  for (int j = tid; j < 1024; j += 256) s += part[j];
#pragma unroll
  for (int o = 32; o; o >>= 1) s += __shfl_down(s, o);
  __shared__ float sb[4];
  if ((tid & 63) == 0) sb[tid >> 6] = s;
  __syncthreads();
  if (tid == 0) out[0] = (sb[0] + sb[1] + sb[2] + sb[3]) * (1.f / 1024.f);
}

// ---------------------------------------------------------------- launch
extern "C" void kernel_launch(void* const* d_in, const int* in_sizes, int n_in,
                              void* d_out, int out_size, void* d_ws, size_t ws_size,
                              hipStream_t stream)
{
  const int*   idx       = (const int*)d_in[0];
  const int*   tgt       = (const int*)d_in[1];
  const float* E         = (const float*)d_in[2];
  const float* norm_w    = (const float*)d_in[3];
  const float* norm2_w   = (const float*)d_in[4];
  const float* in_proj_w = (const float*)d_in[5];
  const float* conv_w    = (const float*)d_in[6];
  const float* conv_b    = (const float*)d_in[7];
  const float* dt_bias   = (const float*)d_in[8];
  const float* A_log     = (const float*)d_in[9];
  const float* Dp        = (const float*)d_in[10];
  const float* gnorm_w   = (const float*)d_in[11];
  const float* out_proj_w= (const float*)d_in[12];
  const float* fc1_w     = (const float*)d_in[13];
  const float* fc2_w     = (const float*)d_in[14];
  const float* norm_f_w  = (const float*)d_in[15];
  float* logits = (float*)d_out;
  (void)in_sizes; (void)n_in; (void)out_size; (void)ws_size;

  char* W = (char*)d_ws;
  size_t off = 0;
  auto A8 = [&](size_t bytes) { void* p = W + off; off = (off + bytes + 255) & ~(size_t)255; return p; };
  float* hbuf   = (float*)A8((size_t)1024 * 1024 * 4);
  u16*   xnormb = (u16*)  A8((size_t)1024 * 1024 * 2);
  u16*   gatedb = (u16*)  A8((size_t)1024 * 2048 * 2);
  u16*   glub   = (u16*)  A8((size_t)1024 * 4096 * 2);
  float* dtsp   = (float*)A8((size_t)1024 * 32 * 4);
  float* dag    = (float*)A8((size_t)1024 * 32 * 4);
  float* pref   = (float*)A8((size_t)1024 * 32 * 4);
  float* dacum  = (float*)A8((size_t)2048 * 4);
  float* lpart  = (float*)A8((size_t)1024 * 4);
  float* lsebuf = (float*)A8((size_t)1024 * NBLK_V * 2 * 4);
  u16*   wip    = (u16*)  A8((size_t)2 * 4352 * 1024 * 2);
  u16*   wop    = (u16*)  A8((size_t)2 * 1024 * 2048 * 2);
  u16*   wfc1   = (u16*)  A8((size_t)2 * 8192 * 1024 * 2);
  u16*   wfc2   = (u16*)  A8((size_t)2 * 1024 * 4096 * 2);
  // shared span: layer temporaries; Ebf aliases it after layers are done
  char*  span   = (char*)A8((size_t)117964800);
  float* big0   = (float*)(span);                          // 17.4 MB (1024x4256)
  float* xbc    = (float*)(span + 33554432);               // 8.9 MB
  float* yb     = (float*)(span + 33554432 + 8912896);     // 8 MB
  float* Sloc   = (float*)(span + 33554432 + 8912896 + 8388608);
  float* Sin    = (float*)((char*)Sloc + 33554432);
  float* part   = Sloc;                                    // splitK slices alias
  u16*   Ebf    = (u16*)span;                              // 100 MB alias (51200x1024)

  dim3 b256(256), b512(512);

  k_cvt8_pad<<<dim3((4352*1024/8 + 255)/256), b256, 0, stream>>>(
      in_proj_w, wip, 4352*1024/8, 4256*1024/8);
  k_cvt8_pad<<<dim3((4352*1024/8 + 255)/256), b256, 0, stream>>>(
      in_proj_w + (size_t)4256*1024, wip + (size_t)4352*1024, 4352*1024/8, 4256*1024/8);
  k_cvt8<<<dim3(2*1024*2048/8/256), b256, 0, stream>>>(out_proj_w, wop, 2*1024*2048/8);
  k_cvt_fc1<<<dim3(2*8192*1024/8/256), b256, 0, stream>>>(fc1_w, wfc1, 2*8192*1024/8);
  k_cvt8<<<dim3(2*1024*4096/8/256), b256, 0, stream>>>(fc2_w, wfc2, 2*1024*4096/8);

  k_ln_embed<<<1024, b256, 0, stream>>>(idx, E, norm_w, hbuf, xnormb);

  const float* nw_next[2] = { norm_w + 1024, norm_f_w };
  for (int L = 0; L < 2; ++L) {
    gemm_bf16<<<dim3(8, 34, 1), b256, 0, stream>>>(
        xnormb, wip + (size_t)L * 4352 * 1024, big0, DPROJ, 1024, 1024);
    k_convdt<<<dim3(9, 1024), b256, 0, stream>>>(
        big0, conv_w + L * CONVDIM * 4, conv_b + L * CONVDIM,
        dt_bias + L * 32, A_log + L * 32, xbc, dtsp, dag);
    k_scan_local<<<dim3(NCHUNK, 32), b256, 0, stream>>>(xbc, dtsp, dag, yb, Sloc, pref, dacum);
    k_chain<<<512, b256, 0, stream>>>(Sloc, dacum, Sin);
    k_scan_fix<<<dim3(NCHUNK, 32), b256, 0, stream>>>(xbc, pref, Sin, Dp + L * 32, yb);
    k_gated_rms<<<1024, b256, 0, stream>>>(yb, big0, gnorm_w + L * 2048, gatedb);
    gemm_bf16<<<dim3(8, 8, 4), b256, 0, stream>>>(
        gatedb, wop + (size_t)L * 1024 * 2048, part, 1024, 2048, 512);
    k_red_ln<<<1024, b256, 0, stream>>>(part, 4, hbuf, norm2_w + L * 1024, xnormb);
    gemm256<<<dim3(4, 64, 1), b512, 0, stream>>>(
        xnormb, wfc1 + (size_t)L * 8192 * 1024, nullptr, 8192, 1024,
        nullptr, 0, 64, glub);
    gemm_bf16<<<dim3(8, 8, 8), b256, 0, stream>>>(
        glub, wfc2 + (size_t)L * 1024 * 4096, part, 1024, 4096, 512);
    k_red_ln<<<1024, b256, 0, stream>>>(part, 8, hbuf, nw_next[L], xnormb);
  }

  k_cvt8_pad<<<dim3((VOCABP*1024/8 + 255)/256), b256, 0, stream>>>(
      E, Ebf, VOCABP*1024/8, VOCAB*1024/8);
  gemm256<<<dim3(4 * NBLK_V, 1, 1), b512, 0, stream>>>(
      xnormb, Ebf, logits, VOCAB, 1024, lsebuf, 1, NBLK_V, nullptr);
  k_loss_final<<<1024, b256, 0, stream>>>(lsebuf, logits, tgt, lpart);
  k_loss_mean<<<1, b256, 0, stream>>>(lpart, logits + (size_t)1024 * VOCAB);
}

// Round 13
// 776.346 us; speedup vs baseline: 1.2420x; 1.0184x over previous
//
#include <hip/hip_runtime.h>
#include <cmath>

#define DMODEL  1024
#define DINNER  2048
#define NHEADS  32
#define CONVDIM 2176
#define DPROJ   4256
#define VOCAB   50257
#define NBLK_V  400            // LM-head n-blocks (padded: 400*128 = 51200 rows)
#define VOCABP  (NBLK_V * 128)
#define CLEN    32
#define NCHUNK  32

typedef float f32x4 __attribute__((ext_vector_type(4)));
typedef float f32x2 __attribute__((ext_vector_type(2)));
typedef unsigned short u16;
typedef u16 u16x4 __attribute__((ext_vector_type(4)));
typedef u16 u16x8 __attribute__((ext_vector_type(8)));
typedef __bf16 bf16x8 __attribute__((ext_vector_type(8)));

__device__ __forceinline__ u16 f2bf(float f) {
  unsigned u = __builtin_bit_cast(unsigned, f);
  u += 0x7FFFu + ((u >> 16) & 1u);
  return (u16)(u >> 16);
}
__device__ __forceinline__ float silu_f(float x) { return x / (1.f + expf(-x)); }

__device__ __forceinline__ void gload16(const u16* g, u16* l) {
  __builtin_amdgcn_global_load_lds(
      (const __attribute__((address_space(1))) void*)g,
      (__attribute__((address_space(3))) void*)l,
      16, 0, 0);
}
__device__ __forceinline__ void vm_wait0() { asm volatile("s_waitcnt vmcnt(0)" ::: "memory"); }

// ---------------------------------------------------------------- 128x128 GEMM
// R7-proven: 4 waves, BK=32, 3-deep LDS, counted vmcnt(4); bf16 A and B.
// Swizzle: 64B rows, phys chunk = data ^ ((row>>1)&3); conflict-free.
__global__ __launch_bounds__(256) void gemm_bf16(
    const u16* __restrict__ A, const u16* __restrict__ B,
    float* __restrict__ C, int N, int K, int kslice)
{
  __shared__ alignas(128) u16 As[3 * 4096];
  __shared__ alignas(128) u16 Bs[3 * 4096];
  const int tid = threadIdx.x;
  const int m0 = blockIdx.x << 7;
  const int n0 = blockIdx.y << 7;
  const int lane = tid & 63, wid = tid >> 6;
  const int wm = (wid >> 1) << 6, wn = (wid & 1) << 6;
  const int lr = lane & 15, kg = lane >> 4;

  const int srow = wid * 16 + (lane >> 2);
  const int scol = ((lane & 3) ^ ((lane >> 3) & 3)) << 3;
  const u16* gA = A + (size_t)(m0 + srow) * K + scol;
  const u16* gB = B + (size_t)(n0 + srow) * K + scol;

  f32x4 acc[4][4];
#pragma unroll
  for (int i = 0; i < 4; ++i)
#pragma unroll
    for (int j = 0; j < 4; ++j) acc[i][j] = (f32x4){0.f, 0.f, 0.f, 0.f};

  const int kb = blockIdx.z * kslice;
  const int nt = kslice >> 5;

  auto stage = [&](int buf, int t) {
    const int ko = kb + (t << 5);
#pragma unroll
    for (int i = 0; i < 2; ++i) {
      gload16(gA + ko + (size_t)i * 64 * K, &As[buf * 4096 + i * 2048 + wid * 512]);
      gload16(gB + ko + (size_t)i * 64 * K, &Bs[buf * 4096 + i * 2048 + wid * 512]);
    }
  };

  stage(0, 0);
  stage(1, 1);
  int b0 = 0, b1 = 1, b2 = 2;
  const int cxr = (lr >> 1) & 3;
  for (int t = 0; t < nt; ++t) {
    if (t == nt - 1) vm_wait0();
    else             asm volatile("s_waitcnt vmcnt(4)" ::: "memory");
    __builtin_amdgcn_s_barrier();
    if (t + 2 < nt) stage(b2, t + 2);
    bf16x8 af[4], bfr[4];
    const int po = (kg ^ cxr) << 3;
#pragma unroll
    for (int f = 0; f < 4; ++f) {
      af[f]  = *(const bf16x8*)&As[b0 * 4096 + (wm + f * 16 + lr) * 32 + po];
      bfr[f] = *(const bf16x8*)&Bs[b0 * 4096 + (wn + f * 16 + lr) * 32 + po];
    }
#pragma unroll
    for (int i = 0; i < 4; ++i)
#pragma unroll
      for (int j = 0; j < 4; ++j)
        acc[i][j] = __builtin_amdgcn_mfma_f32_16x16x32_bf16(af[i], bfr[j], acc[i][j], 0, 0, 0);
    int tmp = b0; b0 = b1; b1 = b2; b2 = tmp;
  }

  const int mr = (lane >> 4) << 2;
  const int nc = lane & 15;
  float* Cw = C + (gridDim.z > 1 ? (size_t)blockIdx.z * 1024 * N : 0);
#pragma unroll
  for (int i = 0; i < 4; ++i)
#pragma unroll
    for (int j = 0; j < 4; ++j) {
      int n = n0 + wn + j * 16 + nc;
      if (n < N) {
#pragma unroll
        for (int e = 0; e < 4; ++e)
          Cw[(size_t)(m0 + wm + i * 16 + mr + e) * N + n] = acc[i][j][e];
      }
    }
}

// ---------------------------------------------------------------- 256x128 GEMM
// R7-proven: 8 waves, BK=32, 3-deep, counted vmcnt(3).
// swz=1 (LM head): 1-D grid 4m x 400n XCD-bijective; lsepart LSE partials.
// glu_out: fc1 fusion (interleaved y/g rows; epilogue emits bf16 y*silu(g)).
__global__ __launch_bounds__(512) void gemm256(
    const u16* __restrict__ A, const u16* __restrict__ B,
    float* __restrict__ C, int N, int K,
    float* __restrict__ lsepart, int swz, int nblk,
    u16* __restrict__ glu_out)
{
  __shared__ alignas(128) u16 As[3 * 8192];   // 3 x 256x32
  __shared__ alignas(128) u16 Bs[3 * 4096];   // 3 x 128x32
  const int tid = threadIdx.x;
  int m0, n0;
  if (swz) {
    int bid = blockIdx.x;
    m0 = ((bid >> 3) & 3) << 8;
    n0 = ((bid & 7) + ((bid >> 5) << 3)) << 7;
  } else {
    m0 = blockIdx.x << 8;
    n0 = blockIdx.y << 7;
  }
  const int lane = tid & 63, wid = tid >> 6;       // 8 waves
  const int wm = (wid >> 1) << 6, wn = (wid & 1) << 6;
  const int lr = lane & 15, kg = lane >> 4;

  const int srow = wid * 16 + (lane >> 2);         // 128 rows per issue
  const int scol = ((lane & 3) ^ ((lane >> 3) & 3)) << 3;
  const u16* gA = A + (size_t)(m0 + srow) * K + scol;
  const u16* gB = B + (size_t)(n0 + srow) * K + scol;

  f32x4 acc[4][4];
#pragma unroll
  for (int i = 0; i < 4; ++i)
#pragma unroll
    for (int j = 0; j < 4; ++j) acc[i][j] = (f32x4){0.f, 0.f, 0.f, 0.f};

  const int nt = K >> 5;

  auto stage = [&](int buf, int t) {
    const int ko = t << 5;
    gload16(gA + ko,                     &As[buf * 8192 + wid * 512]);
    gload16(gA + ko + (size_t)128 * K,   &As[buf * 8192 + 4096 + wid * 512]);
    gload16(gB + ko,                     &Bs[buf * 4096 + wid * 512]);
  };

  stage(0, 0);
  stage(1, 1);
  int b0 = 0, b1 = 1, b2 = 2;
  const int cxr = (lr >> 1) & 3;
  for (int t = 0; t < nt; ++t) {
    if (t == nt - 1) vm_wait0();
    else             asm volatile("s_waitcnt vmcnt(3)" ::: "memory");
    __builtin_amdgcn_s_barrier();
    if (t + 2 < nt) stage(b2, t + 2);
    bf16x8 af[4], bfr[4];
    const int po = (kg ^ cxr) << 3;
#pragma unroll
    for (int f = 0; f < 4; ++f) {
      af[f]  = *(const bf16x8*)&As[b0 * 8192 + (wm + f * 16 + lr) * 32 + po];
      bfr[f] = *(const bf16x8*)&Bs[b0 * 4096 + (wn + f * 16 + lr) * 32 + po];
    }
#pragma unroll
    for (int i = 0; i < 4; ++i)
#pragma unroll
      for (int j = 0; j < 4; ++j)
        acc[i][j] = __builtin_amdgcn_mfma_f32_16x16x32_bf16(af[i], bfr[j], acc[i][j], 0, 0, 0);
    int tmp = b0; b0 = b1; b1 = b2; b2 = tmp;
  }

  const int mr = (lane >> 4) << 2;
  const int nc = lane & 15;

  if (glu_out) {
#pragma unroll
    for (int i = 0; i < 4; ++i)
#pragma unroll
      for (int j = 0; j < 4; ++j)
#pragma unroll
        for (int e = 0; e < 4; ++e) {
          float v = acc[i][j][e];
          float p = __shfl_xor(v, 1);
          if (!(nc & 1)) {
            int q = (n0 + wn + j * 16 + nc) >> 1;
            int row = m0 + wm + i * 16 + mr + e;
            glu_out[(size_t)row * 4096 + q] = f2bf(v * silu_f(p));
          }
        }
    return;
  }

#pragma unroll
  for (int i = 0; i < 4; ++i)
#pragma unroll
    for (int j = 0; j < 4; ++j) {
      int n = n0 + wn + j * 16 + nc;
      if (n < N) {
#pragma unroll
        for (int e = 0; e < 4; ++e)
          C[(size_t)(m0 + wm + i * 16 + mr + e) * N + n] = acc[i][j][e];
      }
    }

  if (lsepart) {
    __syncthreads();
    float* Ls = (float*)As;    // [256 rows][2 halves][2] = 4KB
#pragma unroll
    for (int i = 0; i < 4; ++i)
#pragma unroll
      for (int e = 0; e < 4; ++e) {
        float pm = -1e30f;
#pragma unroll
        for (int j = 0; j < 4; ++j) {
          int n = n0 + wn + j * 16 + nc;
          if (n < N) pm = fmaxf(pm, acc[i][j][e]);
        }
#pragma unroll
        for (int o = 1; o < 16; o <<= 1) pm = fmaxf(pm, __shfl_xor(pm, o));
        float ps = 0.f;
#pragma unroll
        for (int j = 0; j < 4; ++j) {
          int n = n0 + wn + j * 16 + nc;
          if (n < N) ps += expf(acc[i][j][e] - pm);
        }
#pragma unroll
        for (int o = 1; o < 16; o <<= 1) ps += __shfl_xor(ps, o);
        if (nc == 0) {
          int row = wm + i * 16 + mr + e;
          Ls[row * 4 + (wid & 1) * 2] = pm;
          Ls[row * 4 + (wid & 1) * 2 + 1] = ps;
        }
      }
    __syncthreads();
    if (tid < 256) {
      float pa = Ls[tid * 4], sa = Ls[tid * 4 + 1];
      float pb = Ls[tid * 4 + 2], sb = Ls[tid * 4 + 3];
      float M = fmaxf(pa, pb);
      float S = sa * expf(pa - M) + sb * expf(pb - M);
      ((f32x2*)lsepart)[(size_t)(m0 + tid) * nblk + (n0 >> 7)] = (f32x2){M, S};
    }
  }
}

// ---------------------------------------------------------------- conversions
// single merged kernel: all weight buffers -> bf16 (+pad / +fc1 interleave)
// flat u16x8 ranges: [0,557056) wipL0, [557056,1114112) wipL1,
// [1114112,1638400) wop, [1638400,3735552) wfc1, [3735552,4784128) wfc2.
__global__ void k_cvt_all(const float* __restrict__ ip, const float* __restrict__ op,
                          const float* __restrict__ f1, const float* __restrict__ f2,
                          u16* __restrict__ wip, u16* __restrict__ wop,
                          u16* __restrict__ wfc1, u16* __restrict__ wfc2)
{
  int i = blockIdx.x * 256 + threadIdx.x;
  if (i >= 4784128) return;
  if (i < 1114112) {                       // in_proj, padded 4256->4352 rows
    int L = (i >= 557056) ? 1 : 0;
    int j = i - L * 557056;
    u16x8 o = {0, 0, 0, 0, 0, 0, 0, 0};
    if (j < 544768) {                      // 4256*1024/8
      const f32x4* s = (const f32x4*)(ip + (size_t)L * 4358144) + (size_t)j * 2;
      f32x4 a = s[0], b = s[1];
      o = (u16x8){ f2bf(a[0]), f2bf(a[1]), f2bf(a[2]), f2bf(a[3]),
                   f2bf(b[0]), f2bf(b[1]), f2bf(b[2]), f2bf(b[3]) };
    }
    ((u16x8*)(wip + (size_t)L * 4456448))[j] = o;
  } else if (i < 1638400) {                // out_proj plain
    int j = i - 1114112;
    const f32x4* s = (const f32x4*)op + (size_t)j * 2;
    f32x4 a = s[0], b = s[1];
    ((u16x8*)wop)[j] = (u16x8){ f2bf(a[0]), f2bf(a[1]), f2bf(a[2]), f2bf(a[3]),
                                f2bf(b[0]), f2bf(b[1]), f2bf(b[2]), f2bf(b[3]) };
  } else if (i < 3735552) {                // fc1 with y/g row interleave
    int j = i - 1638400;
    const f32x4* s = (const f32x4*)f1 + (size_t)j * 2;
    f32x4 a = s[0], b = s[1];
    u16x8 o = { f2bf(a[0]), f2bf(a[1]), f2bf(a[2]), f2bf(a[3]),
                f2bf(b[0]), f2bf(b[1]), f2bf(b[2]), f2bf(b[3]) };
    int R = j >> 7, col8 = j & 127;
    int layer = R >> 13, r = R & 8191;
    int dstr = (r < 4096) ? (r << 1) : (((r - 4096) << 1) | 1);
    ((u16x8*)wfc1)[((size_t)(layer << 13) + dstr) * 128 + col8] = o;
  } else {                                 // fc2 plain
    int j = i - 3735552;
    const f32x4* s = (const f32x4*)f2 + (size_t)j * 2;
    f32x4 a = s[0], b = s[1];
    ((u16x8*)wfc2)[j] = (u16x8){ f2bf(a[0]), f2bf(a[1]), f2bf(a[2]), f2bf(a[3]),
                                 f2bf(b[0]), f2bf(b[1]), f2bf(b[2]), f2bf(b[3]) };
  }
}

// E -> padded bf16 (runs after layers; dst aliases dead layer temporaries)
__global__ void k_cvt8_pad(const float* __restrict__ src, u16* __restrict__ dst,
                           int n8, int srcN8) {
  int i = blockIdx.x * 256 + threadIdx.x;
  if (i >= n8) return;
  u16x8 o;
  if (i < srcN8) {
    f32x4 a = ((const f32x4*)src)[i * 2];
    f32x4 b = ((const f32x4*)src)[i * 2 + 1];
    o = (u16x8){ f2bf(a[0]), f2bf(a[1]), f2bf(a[2]), f2bf(a[3]),
                 f2bf(b[0]), f2bf(b[1]), f2bf(b[2]), f2bf(b[3]) };
  } else {
    o = (u16x8){0, 0, 0, 0, 0, 0, 0, 0};
  }
  ((u16x8*)dst)[i] = o;
}

// ---------------------------------------------------------------- fused LN
__device__ __forceinline__ void ln_write(f32x4 v, const float* __restrict__ w,
                                         u16* __restrict__ out, int t, int tid) {
  float s = v[0] + v[1] + v[2] + v[3];
  float sq = v[0]*v[0] + v[1]*v[1] + v[2]*v[2] + v[3]*v[3];
#pragma unroll
  for (int o = 32; o; o >>= 1) { s += __shfl_down(s, o); sq += __shfl_down(sq, o); }
  __shared__ float sb[4], qb[4];
  if ((tid & 63) == 0) { sb[tid >> 6] = s; qb[tid >> 6] = sq; }
  __syncthreads();
  s = sb[0] + sb[1] + sb[2] + sb[3];
  sq = qb[0] + qb[1] + qb[2] + qb[3];
  float mu = s * (1.f / 1024.f);
  float rstd = rsqrtf(sq * (1.f / 1024.f) - mu * mu + 1e-5f);
  u16x4 o;
#pragma unroll
  for (int e = 0; e < 4; ++e) o[e] = f2bf((v[e] - mu) * rstd * w[tid * 4 + e]);
  ((u16x4*)out)[t * 256 + tid] = o;
}

__global__ void k_ln_embed(const int* __restrict__ idx, const float* __restrict__ E,
                           const float* __restrict__ w, float* __restrict__ hbuf,
                           u16* __restrict__ out) {
  int t = blockIdx.x, tid = threadIdx.x;
  f32x4 v = ((const f32x4*)(E + (size_t)idx[t] * DMODEL))[tid];
  ((f32x4*)hbuf)[t * 256 + tid] = v;
  ln_write(v, w, out, t, tid);
}

__global__ void k_red_ln(const float* __restrict__ part, int S,
                         float* __restrict__ hbuf, const float* __restrict__ w,
                         u16* __restrict__ out) {
  int t = blockIdx.x, tid = threadIdx.x;
  f32x4 v = ((const f32x4*)hbuf)[t * 256 + tid];
  for (int k = 0; k < S; ++k)
    v += ((const f32x4*)part)[(size_t)k * 262144 + t * 256 + tid];
  ((f32x4*)hbuf)[t * 256 + tid] = v;
  ln_write(v, w, out, t, tid);
}

// ---------------------------------------------------------------- conv + dt
__global__ void k_convdt(const float* __restrict__ zx, const float* __restrict__ cw,
                         const float* __restrict__ cb, const float* __restrict__ dtb,
                         const float* __restrict__ alog, float* __restrict__ xbc,
                         float* __restrict__ dtsp, float* __restrict__ dag) {
  int t = blockIdx.y, x = blockIdx.x, tid = threadIdx.x;
  if (x < 8 || tid < 128) {
    int c = x * 256 + tid;
    float acc = cb[c];
#pragma unroll
    for (int k = 0; k < 4; ++k) {
      int tt = t + k - 3;
      if (tt >= 0) acc += zx[(size_t)tt * DPROJ + 2048 + c] * cw[c * 4 + k];
    }
    xbc[(size_t)t * CONVDIM + c] = silu_f(acc);
  } else if (tid < 160) {
    int hh = tid - 128;
    float raw = zx[(size_t)t * DPROJ + 4224 + hh] + dtb[hh];
    float sp = raw > 20.f ? raw : log1pf(expf(raw));
    dtsp[t * 32 + hh] = sp;
    dag[t * 32 + hh] = expf(-expf(alog[hh]) * sp);
  }
}

// ---------------------------------------------------------------- chunked scan
__global__ __launch_bounds__(256) void k_scan_local(
    const float* __restrict__ xbc, const float* __restrict__ dtsp,
    const float* __restrict__ dag, float* __restrict__ yb, float* __restrict__ Sloc,
    float* __restrict__ pref, float* __restrict__ dacum)
{
  int c = blockIdx.x, hh = blockIdx.y;
  int tid = threadIdx.x;
  int p = tid >> 2, ng = tid & 3, n0 = ng << 4;
  float st[16];
#pragma unroll
  for (int j = 0; j < 16; ++j) st[j] = 0.f;
  float P = 1.f;
  for (int s_ = 0; s_ < CLEN; ++s_) {
    int t = c * CLEN + s_;
    float dA = dag[t * 32 + hh];
    P *= dA;
    if (tid == 0) pref[t * 32 + hh] = P;
    float coef = dtsp[t * 32 + hh] * xbc[(size_t)t * CONVDIM + hh * 64 + p];
    const f32x4* B4 = (const f32x4*)&xbc[(size_t)t * CONVDIM + 2048 + n0];
    const f32x4* C4 = (const f32x4*)&xbc[(size_t)t * CONVDIM + 2112 + n0];
    float y = 0.f;
#pragma unroll
    for (int q = 0; q < 4; ++q) {
      f32x4 b = B4[q], cc = C4[q];
#pragma unroll
      for (int e = 0; e < 4; ++e) {
        int j = q * 4 + e;
        st[j] = dA * st[j] + coef * b[e];
        y += st[j] * cc[e];
      }
    }
    y += __shfl_xor(y, 1);
    y += __shfl_xor(y, 2);
    if (ng == 0) yb[(size_t)t * DINNER + hh * 64 + p] = y;
  }
  if (tid == 0) dacum[c * 32 + hh] = P;
  float* Sp = Sloc + ((size_t)(c * 32 + hh) * 64 + p) * 64 + n0;
#pragma unroll
  for (int q = 0; q < 4; ++q)
    *(f32x4*)(Sp + q * 4) = (f32x4){ st[q*4], st[q*4+1], st[q*4+2], st[q*4+3] };
}

__global__ void k_chain(const float* __restrict__ Sloc, const float* __restrict__ dacum,
                        float* __restrict__ Sin) {
  int e = blockIdx.x * 256 + threadIdx.x;  // 131072
  int hh = e >> 12;
  float S = 0.f;
  for (int c = 0; c < NCHUNK; c += 8) {
    float sl[8], dd[8];
#pragma unroll
    for (int j = 0; j < 8; ++j) sl[j] = Sloc[(size_t)(c + j) * 131072 + e];
#pragma unroll
    for (int j = 0; j < 8; ++j) dd[j] = dacum[(c + j) * 32 + hh];
#pragma unroll
    for (int j = 0; j < 8; ++j) {
      Sin[(size_t)(c + j) * 131072 + e] = S;
      S = dd[j] * S + sl[j];
    }
  }
}

__global__ __launch_bounds__(256) void k_scan_fix(
    const float* __restrict__ xbc, const float* __restrict__ pref,
    const float* __restrict__ Sin, const float* __restrict__ Dp,
    float* __restrict__ yb)
{
  __shared__ float Sl[64 * 68];
  int c = blockIdx.x, hh = blockIdx.y;
  int tid = threadIdx.x;
  for (int i = 0; i < 16; ++i) {
    int e = i * 256 + tid;
    Sl[(e >> 6) * 68 + (e & 63)] = Sin[(size_t)(c * 32 + hh) * 4096 + e];
  }
  __syncthreads();
  int p = tid >> 2, ng = tid & 3, n0 = ng << 4;
  float Dh = Dp[hh];
  for (int s_ = 0; s_ < CLEN; ++s_) {
    int t = c * CLEN + s_;
    const f32x4* C4 = (const f32x4*)&xbc[(size_t)t * CONVDIM + 2112 + n0];
    float yc = 0.f;
#pragma unroll
    for (int q = 0; q < 4; ++q) {
      f32x4 cc = C4[q];
#pragma unroll
      for (int e = 0; e < 4; ++e) yc += Sl[p * 68 + n0 + q * 4 + e] * cc[e];
    }
    yc += __shfl_xor(yc, 1);
    yc += __shfl_xor(yc, 2);
    if (ng == 0) {
      size_t oy = (size_t)t * DINNER + hh * 64 + p;
      yb[oy] = yb[oy] + pref[t * 32 + hh] * yc + Dh * xbc[(size_t)t * CONVDIM + hh * 64 + p];
    }
  }
}

__global__ void k_gated_rms(const float* __restrict__ yb, const float* __restrict__ zx,
                            const float* __restrict__ gw, u16* __restrict__ out) {
  int t = blockIdx.x, tid = threadIdx.x;
  float v[8], ss = 0.f;
#pragma unroll
  for (int i = 0; i < 8; ++i) {
    int j = tid + i * 256;
    float z = zx[(size_t)t * DPROJ + j];
    float vv = yb[(size_t)t * DINNER + j] * silu_f(z);
    v[i] = vv; ss += vv * vv;
  }
#pragma unroll
  for (int o = 32; o; o >>= 1) ss += __shfl_down(ss, o);
  __shared__ float sb[4];
  if ((tid & 63) == 0) sb[tid >> 6] = ss;
  __syncthreads();
  ss = sb[0] + sb[1] + sb[2] + sb[3];
  float rstd = rsqrtf(ss * (1.f / 2048.f) + 1e-5f);
#pragma unroll
  for (int i = 0; i < 8; ++i) {
    int j = tid + i * 256;
    out[(size_t)t * DINNER + j] = f2bf(v[i] * rstd * gw[j]);
  }
}

// ---------------------------------------------------------------- loss
__global__ void k_loss_final(const float* __restrict__ lsepart,
                             const float* __restrict__ logits,
                             const int* __restrict__ tgt, float* __restrict__ part) {
  int t = blockIdx.x, tid = threadIdx.x;
  float m = -1e30f, s = 0.f;
  for (int nb = tid; nb < NBLK_V; nb += 256) {
    f32x2 v = ((const f32x2*)lsepart)[(size_t)t * NBLK_V + nb];
    float M = fmaxf(m, v[0]);
    s = s * expf(m - M) + v[1] * expf(v[0] - M);
    m = M;
  }
#pragma unroll
  for (int o = 32; o; o >>= 1) {
    float m2 = __shfl_down(m, o), s2 = __shfl_down(s, o);
    float M = fmaxf(m, m2);
    s = s * expf(m - M) + s2 * expf(m2 - M);
    m = M;
  }
  __shared__ float ms[4], ssh[4];
  if ((tid & 63) == 0) { ms[tid >> 6] = m; ssh[tid >> 6] = s; }
  __syncthreads();
  if (tid == 0) {
    float M = ms[0], S = ssh[0];
    for (int w = 1; w < 4; ++w) {
      float M2 = fmaxf(M, ms[w]);
      S = S * expf(M - M2) + ssh[w] * expf(ms[w] - M2);
      M = M2;
    }
    part[t] = (M + logf(S)) - logits[(size_t)t * VOCAB + tgt[t]];
  }
}

__global__ void k_loss_mean(const float* __restrict__ part, float* __restrict__ out) {
  int tid = threadIdx.x;
  float s = 0.f;
  for (int j = tid; j < 1024; j += 256) s += part[j];
#pragma unroll
  for (int o = 32; o; o >>= 1) s += __shfl_down(s, o);
  __shared__ float sb[4];
  if ((tid & 63) == 0) sb[tid >> 6] = s;
  __syncthreads();
  if (tid == 0) out[0] = (sb[0] + sb[1] + sb[2] + sb[3]) * (1.f / 1024.f);
}

// ---------------------------------------------------------------- launch
extern "C" void kernel_launch(void* const* d_in, const int* in_sizes, int n_in,
                              void* d_out, int out_size, void* d_ws, size_t ws_size,
                              hipStream_t stream)
{
  const int*   idx       = (const int*)d_in[0];
  const int*   tgt       = (const int*)d_in[1];
  const float* E         = (const float*)d_in[2];
  const float* norm_w    = (const float*)d_in[3];
  const float* norm2_w   = (const float*)d_in[4];
  const float* in_proj_w = (const float*)d_in[5];
  const float* conv_w    = (const float*)d_in[6];
  const float* conv_b    = (const float*)d_in[7];
  const float* dt_bias   = (const float*)d_in[8];
  const float* A_log     = (const float*)d_in[9];
  const float* Dp        = (const float*)d_in[10];
  const float* gnorm_w   = (const float*)d_in[11];
  const float* out_proj_w= (const float*)d_in[12];
  const float* fc1_w     = (const float*)d_in[13];
  const float* fc2_w     = (const float*)d_in[14];
  const float* norm_f_w  = (const float*)d_in[15];
  float* logits = (float*)d_out;
  (void)in_sizes; (void)n_in; (void)out_size; (void)ws_size;

  char* W = (char*)d_ws;
  size_t off = 0;
  auto A8 = [&](size_t bytes) { void* p = W + off; off = (off + bytes + 255) & ~(size_t)255; return p; };
  float* hbuf   = (float*)A8((size_t)1024 * 1024 * 4);
  u16*   xnormb = (u16*)  A8((size_t)1024 * 1024 * 2);
  u16*   gatedb = (u16*)  A8((size_t)1024 * 2048 * 2);
  u16*   glub   = (u16*)  A8((size_t)1024 * 4096 * 2);
  float* dtsp   = (float*)A8((size_t)1024 * 32 * 4);
  float* dag    = (float*)A8((size_t)1024 * 32 * 4);
  float* pref   = (float*)A8((size_t)1024 * 32 * 4);
  float* dacum  = (float*)A8((size_t)2048 * 4);
  float* lpart  = (float*)A8((size_t)1024 * 4);
  float* lsebuf = (float*)A8((size_t)1024 * NBLK_V * 2 * 4);
  u16*   wip    = (u16*)  A8((size_t)2 * 4352 * 1024 * 2);
  u16*   wop    = (u16*)  A8((size_t)2 * 1024 * 2048 * 2);
  u16*   wfc1   = (u16*)  A8((size_t)2 * 8192 * 1024 * 2);
  u16*   wfc2   = (u16*)  A8((size_t)2 * 1024 * 4096 * 2);
  // shared span: layer temporaries; Ebf aliases it after layers are done
  char*  span   = (char*)A8((size_t)117964800);
  float* big0   = (float*)(span);                          // 17.4 MB (1024x4256)
  float* xbc    = (float*)(span + 33554432);               // 8.9 MB
  float* yb     = (float*)(span + 33554432 + 8912896);     // 8 MB
  float* Sloc   = (float*)(span + 33554432 + 8912896 + 8388608);
  float* Sin    = (float*)((char*)Sloc + 33554432);
  float* part   = Sloc;                                    // splitK slices alias
  u16*   Ebf    = (u16*)span;                              // 100 MB alias (51200x1024)

  dim3 b256(256), b512(512);

  k_cvt_all<<<dim3((4784128 + 255) / 256), b256, 0, stream>>>(
      in_proj_w, out_proj_w, fc1_w, fc2_w, wip, wop, wfc1, wfc2);

  k_ln_embed<<<1024, b256, 0, stream>>>(idx, E, norm_w, hbuf, xnormb);

  const float* nw_next[2] = { norm_w + 1024, norm_f_w };
  for (int L = 0; L < 2; ++L) {
    gemm_bf16<<<dim3(8, 34, 1), b256, 0, stream>>>(
        xnormb, wip + (size_t)L * 4352 * 1024, big0, DPROJ, 1024, 1024);
    k_convdt<<<dim3(9, 1024), b256, 0, stream>>>(
        big0, conv_w + L * CONVDIM * 4, conv_b + L * CONVDIM,
        dt_bias + L * 32, A_log + L * 32, xbc, dtsp, dag);
    k_scan_local<<<dim3(NCHUNK, 32), b256, 0, stream>>>(xbc, dtsp, dag, yb, Sloc, pref, dacum);
    k_chain<<<512, b256, 0, stream>>>(Sloc, dacum, Sin);
    k_scan_fix<<<dim3(NCHUNK, 32), b256, 0, stream>>>(xbc, pref, Sin, Dp + L * 32, yb);
    k_gated_rms<<<1024, b256, 0, stream>>>(yb, big0, gnorm_w + L * 2048, gatedb);
    gemm_bf16<<<dim3(8, 8, 4), b256, 0, stream>>>(
        gatedb, wop + (size_t)L * 1024 * 2048, part, 1024, 2048, 512);
    k_red_ln<<<1024, b256, 0, stream>>>(part, 4, hbuf, norm2_w + L * 1024, xnormb);
    gemm256<<<dim3(4, 64, 1), b512, 0, stream>>>(
        xnormb, wfc1 + (size_t)L * 8192 * 1024, nullptr, 8192, 1024,
        nullptr, 0, 64, glub);
    gemm_bf16<<<dim3(8, 8, 8), b256, 0, stream>>>(
        glub, wfc2 + (size_t)L * 1024 * 4096, part, 1024, 4096, 512);
    k_red_ln<<<1024, b256, 0, stream>>>(part, 8, hbuf, nw_next[L], xnormb);
  }

  k_cvt8_pad<<<dim3((VOCABP*1024/8 + 255)/256), b256, 0, stream>>>(
      E, Ebf, VOCABP*1024/8, VOCAB*1024/8);
  gemm256<<<dim3(4 * NBLK_V, 1, 1), b512, 0, stream>>>(
      xnormb, Ebf, logits, VOCAB, 1024, lsebuf, 1, NBLK_V, nullptr);
  k_loss_final<<<1024, b256, 0, stream>>>(lsebuf, logits, tgt, lpart);
  k_loss_mean<<<1, b256, 0, stream>>>(lpart, logits + (size_t)1024 * VOCAB);
}